// Round 6
// baseline (1682.824 us; speedup 1.0000x reference)
//
#include <hip/hip_runtime.h>

#define BB 64
#define TT 2048
#define INW 64
#define HH 256
#define NXB 512                  // xprep blocks
#define RPB ((BB * TT) / NXB)    // 256 rows per xprep block

typedef float v2f __attribute__((ext_vector_type(2)));

__device__ __forceinline__ v2f fma2(v2f a, v2f b, v2f c) {
#if __has_builtin(__builtin_elementwise_fma)
    return __builtin_elementwise_fma(a, b, c);   // -> v_pk_fma_f32
#else
    v2f r; r.x = __builtin_fmaf(a.x, b.x, c.x); r.y = __builtin_fmaf(a.y, b.y, c.y); return r;
#endif
}

__device__ __forceinline__ float fast_tanh(float x) {
    // tanh(x) = 1 - 2/(e^{2x}+1); saturates correctly at +/-inf
    float e = __expf(2.0f * x);
    return 1.0f - 2.0f / (e + 1.0f);
}

// Barrier with LDS-only drain: skips the vmcnt(0) flush __syncthreads() emits,
// so global store-acks / X prefetches never sit on the per-step critical path.
// sched_barrier(0) stops hipcc hoisting post-barrier LDS reads (skill rule #18).
__device__ __forceinline__ void lds_barrier() {
    asm volatile("s_waitcnt lgkmcnt(0)" ::: "memory");
    __builtin_amdgcn_s_barrier();
    __builtin_amdgcn_sched_barrier(0);
}

// ---------------------------------------------------------------------------
// Pre-pass: X[row, h] = sum_j I[row, j] * W_in[h, j] + b[h], row = b*TT + t.
// Hoists the input projection out of the serial scan (it has no dependence on
// the recurrence), so the scan's per-thread weight set drops 80 -> 64 floats
// and fits the 128-reg/wave cap of a 1024-thread block in ARCH VGPRs.
// X is written into the u-region of d_out and overwritten by u during the scan.
// Thread h holds W_in row h (64 f32) in registers; I-row reads are
// wave-uniform (compiler scalarizes to s_load). No LDS, no barriers.
// ---------------------------------------------------------------------------
__global__ __launch_bounds__(256)
void xprep(const float* __restrict__ I,
           const float* __restrict__ W_in,
           const float* __restrict__ bias,
           float* __restrict__ X)
{
    const int h = threadIdx.x;
    const size_t row0 = (size_t)blockIdx.x * RPB;

    v2f w[32];
    {
        const float4* wp = (const float4*)(W_in + (size_t)h * INW);
        #pragma unroll
        for (int i = 0; i < 16; ++i) {
            float4 a = wp[i];
            w[2*i]     = (v2f){a.x, a.y};
            w[2*i + 1] = (v2f){a.z, a.w};
        }
    }
    const float bv = bias[h];

    for (int r = 0; r < RPB; ++r) {
        const float4* ip = (const float4*)(I + (row0 + r) * INW);
        v2f acc0 = {0.f, 0.f}, acc1 = {0.f, 0.f};
        #pragma unroll
        for (int i = 0; i < 16; ++i) {
            float4 iv = ip[i];
            acc0 = fma2(w[2*i],     (v2f){iv.x, iv.y}, acc0);
            acc1 = fma2(w[2*i + 1], (v2f){iv.z, iv.w}, acc1);
        }
        v2f s = acc0 + acc1;
        X[(row0 + r) * HH + h] = s.x + s.y + bv;
    }
}

// ---------------------------------------------------------------------------
// Serial scan. One workgroup per batch, 1024 threads (16 waves, 4/SIMD).
// Thread (h2 = tid & 127, q = tid >> 7 in [0,8)) owns W_rec rows {h2, h2+128}
// x k in [32q, 32q+32): 64 weight floats + ~40 working regs < 128-reg cap ->
// arch-VGPR resident (R1/R3 showed 80+ floats overflow to AGPRs, costing
// ~640 cyc/SIMD/step of v_accvgpr_read on the serial path).
// Per step: 8 wave-uniform ds_read_b128 -> 32 v_pk_fma -> part[q][h] ->
// barrier -> tid<256 combine 8 partials + X[t], update u, store u, write r;
// wave 4 stages X[t+1] (loaded 2 steps ahead) -> barrier. Both barriers are
// lgkm-only. uX aliases X and u_out: X[b,t] is consumed >= 2 barriers before
// u[b,t] overwrites it.
// ---------------------------------------------------------------------------
__global__ __launch_bounds__(1024, 4)
void rnn_scan(const float* __restrict__ x0,
              const float* __restrict__ W_rec,
              float* uX)                      // aliased: X (read) / u_out (write)
{
    __shared__ __align__(16) float r_buf[HH];
    __shared__ __align__(16) float xbuf[2][HH];
    __shared__ float part[8][HH + 8];   // stride 264: 8-bank shift/row

    const int b   = blockIdx.x;
    const int tid = threadIdx.x;
    const int h2  = tid & 127;
    const int q   = tid >> 7;          // wave-uniform (wave w has q = w>>1)
    const int k0  = q * 32;
    const int hA  = h2;
    const int hB  = h2 + 128;
    const int il  = tid - 256;         // wave 4 lanes stage X rows

    // ---- loop-invariant W_rec slice into registers (64 f32 = 32 v2f) ----
    v2f wrA[16], wrB[16];
    {
        const float4* wa = (const float4*)(W_rec + (size_t)hA * HH + k0);
        const float4* wb = (const float4*)(W_rec + (size_t)hB * HH + k0);
        #pragma unroll
        for (int i = 0; i < 8; ++i) {
            float4 a = wa[i], bq = wb[i];
            wrA[2*i]     = (v2f){a.x, a.y};   wrA[2*i + 1] = (v2f){a.z, a.w};
            wrB[2*i]     = (v2f){bq.x, bq.y}; wrB[2*i + 1] = (v2f){bq.z, bq.w};
        }
    }

    // ---- state init ----
    float u = 0.0f;
    if (tid < HH) {
        u = x0[(size_t)b * HH + tid];
        r_buf[tid] = fast_tanh(u);
    }
    if (tid < 64)   // stage X[b,0]
        ((float4*)&xbuf[0][0])[tid] = ((const float4*)(uX + (size_t)b * TT * HH))[tid];
    float4 x_next = {0.f, 0.f, 0.f, 0.f};
    if ((unsigned)il < 64u)  // wave 4: X[b,1] in flight
        x_next = ((const float4*)(uX + ((size_t)b * TT + 1) * HH))[il];
    __syncthreads();

    const float4* rb4 = (const float4*)&r_buf[k0];

    for (int t = 0; t < TT; ++t) {
        // wave 4: issue X[b,t+2] (consumed at the END of step t+1 -> ~2 steps
        // of latency cover; safe vs the u[b,t+2] write in step t+2's phase 2)
        float4 x_fut = {0.f, 0.f, 0.f, 0.f};
        if ((unsigned)il < 64u && (t + 2) < TT)
            x_fut = ((const float4*)(uX + ((size_t)b * TT + t + 2) * HH))[il];

        // ---- partial dot: rows {h2, h2+128}, k in [32q, 32q+32) ----
        v2f aA0 = {0.f,0.f}, aA1 = {0.f,0.f}, aB0 = {0.f,0.f}, aB1 = {0.f,0.f};
        #pragma unroll
        for (int i = 0; i < 8; ++i) {
            float4 r4 = rb4[i];                      // wave-uniform -> LDS broadcast
            v2f r01 = (v2f){r4.x, r4.y}, r23 = (v2f){r4.z, r4.w};
            aA0 = fma2(wrA[2*i],     r01, aA0);
            aA1 = fma2(wrA[2*i + 1], r23, aA1);
            aB0 = fma2(wrB[2*i],     r01, aB0);
            aB1 = fma2(wrB[2*i + 1], r23, aB1);
        }
        v2f sA = aA0 + aA1, sB = aB0 + aB1;
        part[q][hA] = sA.x + sA.y;
        part[q][hB] = sB.x + sB.y;
        lds_barrier();                               // partials visible; r reads done

        if (tid < HH) {
            float d = (((part[0][tid] + part[1][tid]) + (part[2][tid] + part[3][tid])) +
                       ((part[4][tid] + part[5][tid]) + (part[6][tid] + part[7][tid])))
                      + xbuf[t & 1][tid];
            u = 0.8f * u + 0.2f * d;
            uX[((size_t)b * TT + t) * HH + tid] = u;
            r_buf[tid] = fast_tanh(u);
        }
        if ((unsigned)il < 64u && (t + 1) < TT)      // wave 4 publishes X[b,t+1]
            *(float4*)&xbuf[(t + 1) & 1][4 * il] = x_next;
        x_next = x_fut;
        lds_barrier();                               // new r / xbuf visible for t+1
    }
}

// y[b,t,o] = sum_h u[b,t,h] * Wout[o,h] + bout[o]. One wave per (b,t) row.
__global__ __launch_bounds__(256)
void readout(const float* __restrict__ u,
             const float* __restrict__ Wout,
             const float* __restrict__ bout,
             float* __restrict__ y)
{
    const int wid  = threadIdx.x >> 6;
    const int lane = threadIdx.x & 63;
    const size_t row = (size_t)blockIdx.x * 4 + wid;   // < BB*TT

    float4 uv = ((const float4*)(u + row * HH))[lane];
    float4 w0 = ((const float4*)Wout)[lane];
    float4 w1 = ((const float4*)(Wout + HH))[lane];

    float acc0 = uv.x * w0.x + uv.y * w0.y + uv.z * w0.z + uv.w * w0.w;
    float acc1 = uv.x * w1.x + uv.y * w1.y + uv.z * w1.z + uv.w * w1.w;

    #pragma unroll
    for (int m = 32; m >= 1; m >>= 1) {
        acc0 += __shfl_xor(acc0, m, 64);
        acc1 += __shfl_xor(acc1, m, 64);
    }
    if (lane == 0) {
        y[row * 2 + 0] = acc0 + bout[0];
        y[row * 2 + 1] = acc1 + bout[1];
    }
}

extern "C" void kernel_launch(void* const* d_in, const int* in_sizes, int n_in,
                              void* d_out, int out_size, void* d_ws, size_t ws_size,
                              hipStream_t stream) {
    const float* x0    = (const float*)d_in[0];
    const float* I     = (const float*)d_in[1];
    const float* W_in  = (const float*)d_in[2];
    const float* W_rec = (const float*)d_in[3];
    const float* bias  = (const float*)d_in[4];
    const float* Wout  = (const float*)d_in[5];
    const float* bout  = (const float*)d_in[6];

    float* u_out = (float*)d_out;                       // also holds X pre-scan
    float* y_out = u_out + (size_t)BB * TT * HH;

    xprep<<<NXB, 256, 0, stream>>>(I, W_in, bias, u_out);
    rnn_scan<<<BB, 1024, 0, stream>>>(x0, W_rec, u_out);
    readout<<<(BB * TT) / 4, 256, 0, stream>>>(u_out, Wout, bout, y_out);
}